// Round 2
// baseline (231.570 us; speedup 1.0000x reference)
//
#include <hip/hip_runtime.h>
#include <hip/hip_bf16.h>

typedef __bf16 bf16;
typedef bf16 bf16x4 __attribute__((ext_vector_type(4)));
typedef bf16 bf16x8 __attribute__((ext_vector_type(8)));
typedef float f32x4 __attribute__((ext_vector_type(4)));

#define LOG2E 1.44269504088896340736f

__device__ __forceinline__ void gload_lds16(const bf16* g, bf16* l) {
  __builtin_amdgcn_global_load_lds(
      (const __attribute__((address_space(1))) void*)g,
      (__attribute__((address_space(3))) void*)l, 16, 0, 0);
}

// ---------------- fp32 -> bf16 conversion (5 segments in one launch) -------
struct CvtArgs {
  const float* src[5];
  bf16* dst[5];
  int n[5];
};

__global__ __launch_bounds__(256) void cvt_multi(CvtArgs a) {
  const int seg = blockIdx.y;
  const float* __restrict__ s = a.src[seg];
  bf16* __restrict__ d = a.dst[seg];
  const int n = a.n[seg];
  int i = (blockIdx.x * 256 + threadIdx.x) * 4;
  const int stride = gridDim.x * 256 * 4;
  for (; i < n; i += stride) {
    float4 f = *reinterpret_cast<const float4*>(s + i);
    bf16x4 o = {(bf16)f.x, (bf16)f.y, (bf16)f.z, (bf16)f.w};
    *reinterpret_cast<bf16x4*>(d + i) = o;
  }
}

// ---------------- 128x128 bf16 GEMM, C = A * B^T + bias --------------------
// A: [M][K] row-major bf16.  Bw: [N][K] row-major bf16 (i.e. W as stored).
// z = blockIdx.z selects weight/bias/output (fused QKV).
struct GemmBatch {
  const bf16* Bw[3];
  const float* bias[3];
  void* C[3];
};

template <bool OUT_BF16>
__global__ __launch_bounds__(256, 2) void gemm128(const bf16* __restrict__ A,
                                                  GemmBatch gb, int M, int N,
                                                  int K) {
  const int tid = threadIdx.x;
  const int wid = tid >> 6;
  const int lane = tid & 63;
  const int l16 = lane & 15;
  const int hi = lane >> 4;
  const int m0 = blockIdx.x * 128;
  const int n0 = blockIdx.y * 128;
  const int z = blockIdx.z;
  const bf16* __restrict__ Bw = gb.Bw[z];
  const float* __restrict__ bias = gb.bias[z];

  __shared__ bf16 As[128 * 32];
  __shared__ bf16 Bs[128 * 32];

  f32x4 acc[4][4] = {};

  const int wm = (wid >> 1) * 64;
  const int wn = (wid & 1) * 64;

  for (int k0 = 0; k0 < K; k0 += 32) {
    // stage A,B tiles: 8 KiB each, XOR-swizzled (byte ^= (row&3)<<4 within row)
    // via pre-swizzled global source + linear LDS dest (rule #21).
#pragma unroll
    for (int i = 0; i < 2; ++i) {
      const int chunk = wid + 4 * i;               // 0..7, wave-uniform
      const int p = chunk * 1024 + lane * 16;      // physical LDS byte
      const int row = p >> 6;                      // 64B per row (32 bf16)
      const int cb = (p & 48) ^ ((row & 3) << 4);  // logical col byte
      gload_lds16(A + (size_t)(m0 + row) * K + k0 + (cb >> 1), As + chunk * 512);
      gload_lds16(Bw + (size_t)(n0 + row) * K + k0 + (cb >> 1), Bs + chunk * 512);
    }
    __syncthreads();

    bf16x8 af[4], bfr[4];
#pragma unroll
    for (int m = 0; m < 4; ++m) {
      const int r = wm + m * 16 + l16;
      const int pb = r * 64 + ((hi * 16) ^ ((r & 3) << 4));
      af[m] = *reinterpret_cast<const bf16x8*>((const char*)As + pb);
    }
#pragma unroll
    for (int n = 0; n < 4; ++n) {
      const int r = wn + n * 16 + l16;
      const int pb = r * 64 + ((hi * 16) ^ ((r & 3) << 4));
      bfr[n] = *reinterpret_cast<const bf16x8*>((const char*)Bs + pb);
    }
#pragma unroll
    for (int m = 0; m < 4; ++m)
#pragma unroll
      for (int n = 0; n < 4; ++n)
        acc[m][n] =
            __builtin_amdgcn_mfma_f32_16x16x32_bf16(af[m], bfr[n], acc[m][n], 0, 0, 0);
    __syncthreads();
  }

  // epilogue: C/D layout col=lane&15, row=(lane>>4)*4+j
  const int rbase = m0 + wm + hi * 4;
  const int cbase = n0 + wn + l16;
#pragma unroll
  for (int n = 0; n < 4; ++n) {
    const int col = cbase + n * 16;
    const float bv = bias[col];
#pragma unroll
    for (int m = 0; m < 4; ++m) {
#pragma unroll
      for (int j = 0; j < 4; ++j) {
        const int row = rbase + m * 16 + j;
        const float v = acc[m][n][j] + bv;
        if (OUT_BF16)
          ((bf16*)gb.C[z])[(size_t)row * N + col] = (bf16)v;
        else
          ((float*)gb.C[z])[(size_t)row * N + col] = v;
      }
    }
  }
}

// ---------------- causal flash attention -----------------------------------
// Q,K,V,Y: [B*S][1024] bf16, head h in cols h*64..h*64+63.
// Block: (qt, h, b); 4 waves, 16 q-rows/wave; KV tiles of 64.
__global__ __launch_bounds__(256, 2) void attn64(const bf16* __restrict__ Q,
                                                 const bf16* __restrict__ K,
                                                 const bf16* __restrict__ V,
                                                 bf16* __restrict__ Y) {
  const int qt = blockIdx.x;  // 0..31
  const int h = blockIdx.y;   // 0..15
  const int b = blockIdx.z;   // 0..1
  const int tid = threadIdx.x, wid = tid >> 6, lane = tid & 63;
  const int l16 = lane & 15, hi = lane >> 4;
  const int D = 1024;
  const size_t rb = (size_t)b * 2048;

  __shared__ bf16 Vt[64][72];      // V^T tile: Vt[d][kv]
  __shared__ bf16 Pl[4][16][72];   // per-wave P: Pl[w][q_local][kv]

  // Q fragments (hoisted): rows qt*64+wid*16+l16, k = hi*8..+7 per half
  const int qrow = qt * 64 + wid * 16 + l16;
  bf16x8 qf[2];
#pragma unroll
  for (int s = 0; s < 2; ++s)
    qf[s] = *reinterpret_cast<const bf16x8*>(Q + (rb + qrow) * D + h * 64 + s * 32 + hi * 8);

  f32x4 yac[4] = {};
  float mj[4], lj[4];
#pragma unroll
  for (int j = 0; j < 4; ++j) {
    mj[j] = -INFINITY;
    lj[j] = 0.f;
  }

  const int kv_last = qt * 64;                    // start of diagonal supertile
  const int qlast = qt * 64 + wid * 16 + 15;      // wave's max q row
  const float cl2 = 0.125f * LOG2E;               // 1/sqrt(64) * log2(e)

  for (int kv0 = 0; kv0 <= kv_last; kv0 += 64) {
    // ---- stage V^T (4x4 in-register transpose, coalesced global reads) ----
    {
      const int r0 = (tid >> 4) * 4;   // kv sub-row
      const int c4 = (tid & 15) * 4;   // d sub-col
      bf16x4 vr[4];
#pragma unroll
      for (int j = 0; j < 4; ++j)
        vr[j] = *reinterpret_cast<const bf16x4*>(V + (rb + kv0 + r0 + j) * D + h * 64 + c4);
#pragma unroll
      for (int kc = 0; kc < 4; ++kc) {
        bf16x4 w = {vr[0][kc], vr[1][kc], vr[2][kc], vr[3][kc]};
        *reinterpret_cast<bf16x4*>(&Vt[c4 + kc][r0]) = w;
      }
    }
    __syncthreads();

    if (kv0 <= qlast) {  // wave-uniform: skip fully-masked tiles
      // ---- scores: S[16q x 64kv], K frags direct from global -------------
      f32x4 sc[4];
#pragma unroll
      for (int kt = 0; kt < 4; ++kt) {
        const bf16* kr = K + (rb + kv0 + kt * 16 + l16) * D + h * 64 + hi * 8;
        bf16x8 kf0 = *reinterpret_cast<const bf16x8*>(kr);
        bf16x8 kf1 = *reinterpret_cast<const bf16x8*>(kr + 32);
        f32x4 s = {};
        s = __builtin_amdgcn_mfma_f32_16x16x32_bf16(qf[0], kf0, s, 0, 0, 0);
        s = __builtin_amdgcn_mfma_f32_16x16x32_bf16(qf[1], kf1, s, 0, 0, 0);
        sc[kt] = s;
      }
      // ---- causal mask + row max ----
      float pmax[4] = {-INFINITY, -INFINITY, -INFINITY, -INFINITY};
#pragma unroll
      for (int kt = 0; kt < 4; ++kt) {
        const int kvg = kv0 + kt * 16 + l16;
#pragma unroll
        for (int j = 0; j < 4; ++j) {
          const int qg = qt * 64 + wid * 16 + hi * 4 + j;
          if (kvg > qg) sc[kt][j] = -INFINITY;
          pmax[j] = fmaxf(pmax[j], sc[kt][j]);
        }
      }
#pragma unroll
      for (int msk = 1; msk <= 8; msk <<= 1)
#pragma unroll
        for (int j = 0; j < 4; ++j)
          pmax[j] = fmaxf(pmax[j], __shfl_xor(pmax[j], msk));

      // ---- online softmax update (scale folded into exp2 constant) ----
      float al[4], rs[4];
#pragma unroll
      for (int j = 0; j < 4; ++j) {
        const float mn = fmaxf(mj[j], pmax[j]);
        al[j] = exp2f((mj[j] - mn) * cl2);
        mj[j] = mn;
        rs[j] = 0.f;
      }
#pragma unroll
      for (int kt = 0; kt < 4; ++kt)
#pragma unroll
        for (int j = 0; j < 4; ++j) {
          const float p = exp2f((sc[kt][j] - mj[j]) * cl2);
          sc[kt][j] = p;
          rs[j] += p;
        }
#pragma unroll
      for (int msk = 1; msk <= 8; msk <<= 1)
#pragma unroll
        for (int j = 0; j < 4; ++j) rs[j] += __shfl_xor(rs[j], msk);
#pragma unroll
      for (int j = 0; j < 4; ++j) lj[j] = lj[j] * al[j] + rs[j];
#pragma unroll
      for (int dt = 0; dt < 4; ++dt)
#pragma unroll
        for (int j = 0; j < 4; ++j) yac[dt][j] *= al[j];

      // ---- P -> bf16 -> LDS (score layout -> A-frag layout) ----
#pragma unroll
      for (int kt = 0; kt < 4; ++kt)
#pragma unroll
        for (int j = 0; j < 4; ++j)
          Pl[wid][hi * 4 + j][kt * 16 + l16] = (bf16)sc[kt][j];

      // ---- PV: yac[dt] += P[16x64] * V[64x(dt*16..)] ----
#pragma unroll
      for (int half = 0; half < 2; ++half) {
        bf16x8 pf = *reinterpret_cast<const bf16x8*>(&Pl[wid][l16][half * 32 + hi * 8]);
#pragma unroll
        for (int dt = 0; dt < 4; ++dt) {
          bf16x8 vf = *reinterpret_cast<const bf16x8*>(&Vt[dt * 16 + l16][half * 32 + hi * 8]);
          yac[dt] = __builtin_amdgcn_mfma_f32_16x16x32_bf16(pf, vf, yac[dt], 0, 0, 0);
        }
      }
    }
    __syncthreads();
  }

  // ---- epilogue: divide by row sum, write y ----
#pragma unroll
  for (int dt = 0; dt < 4; ++dt)
#pragma unroll
    for (int j = 0; j < 4; ++j) {
      const int row = qt * 64 + wid * 16 + hi * 4 + j;
      const float o = yac[dt][j] / lj[j];
      Y[(rb + row) * D + h * 64 + dt * 16 + l16] = (bf16)o;
    }
}

// ---------------- host launch ----------------------------------------------
extern "C" void kernel_launch(void* const* d_in, const int* in_sizes, int n_in,
                              void* d_out, int out_size, void* d_ws,
                              size_t ws_size, hipStream_t stream) {
  const float* x = (const float*)d_in[0];
  const float* Wq = (const float*)d_in[1];
  const float* bq = (const float*)d_in[2];
  const float* Wk = (const float*)d_in[3];
  const float* bk = (const float*)d_in[4];
  const float* Wv = (const float*)d_in[5];
  const float* bv = (const float*)d_in[6];
  const float* Wp = (const float*)d_in[7];
  const float* bp = (const float*)d_in[8];

  const int BS = 4096;  // B*S
  const int Dm = 1024;

  char* ws = (char*)d_ws;
  bf16* xb = (bf16*)(ws);                                   // 8 MiB
  bf16* wqb = (bf16*)(ws + (size_t)(8 << 20));              // 2 MiB
  bf16* wkb = (bf16*)(ws + (size_t)(10 << 20));             // 2 MiB
  bf16* wvb = (bf16*)(ws + (size_t)(12 << 20));             // 2 MiB
  bf16* wpb = (bf16*)(ws + (size_t)(14 << 20));             // 2 MiB
  bf16* Qb = (bf16*)(ws + (size_t)(16 << 20));              // 8 MiB
  bf16* Kb = (bf16*)(ws + (size_t)(24 << 20));              // 8 MiB
  bf16* Vb = (bf16*)(ws + (size_t)(32 << 20));              // 8 MiB
  bf16* Yb = (bf16*)(ws + (size_t)(40 << 20));              // 8 MiB

  CvtArgs ca;
  ca.src[0] = x;  ca.dst[0] = xb;  ca.n[0] = BS * Dm;
  ca.src[1] = Wq; ca.dst[1] = wqb; ca.n[1] = Dm * Dm;
  ca.src[2] = Wk; ca.dst[2] = wkb; ca.n[2] = Dm * Dm;
  ca.src[3] = Wv; ca.dst[3] = wvb; ca.n[3] = Dm * Dm;
  ca.src[4] = Wp; ca.dst[4] = wpb; ca.n[4] = Dm * Dm;
  cvt_multi<<<dim3(1024, 5), 256, 0, stream>>>(ca);

  GemmBatch gq;
  gq.Bw[0] = wqb; gq.bias[0] = bq; gq.C[0] = Qb;
  gq.Bw[1] = wkb; gq.bias[1] = bk; gq.C[1] = Kb;
  gq.Bw[2] = wvb; gq.bias[2] = bv; gq.C[2] = Vb;
  gemm128<true><<<dim3(32, 8, 3), 256, 0, stream>>>(xb, gq, BS, Dm, Dm);

  attn64<<<dim3(32, 16, 2), 256, 0, stream>>>(Qb, Kb, Vb, Yb);

  GemmBatch gp;
  gp.Bw[0] = wpb; gp.bias[0] = bp; gp.C[0] = d_out;
  gp.Bw[1] = wpb; gp.bias[1] = bp; gp.C[1] = d_out;
  gp.Bw[2] = wpb; gp.bias[2] = bp; gp.C[2] = d_out;
  gemm128<false><<<dim3(32, 8, 1), 256, 0, stream>>>(Yb, gp, BS, Dm, Dm);
}

// Round 4
// 174.688 us; speedup vs baseline: 1.3256x; 1.3256x over previous
//
#include <hip/hip_runtime.h>
#include <hip/hip_bf16.h>

typedef __bf16 bf16;
typedef bf16 bf16x4 __attribute__((ext_vector_type(4)));
typedef bf16 bf16x8 __attribute__((ext_vector_type(8)));
typedef float f32x4 __attribute__((ext_vector_type(4)));
typedef float f32x16 __attribute__((ext_vector_type(16)));
typedef unsigned int u32x4 __attribute__((ext_vector_type(4)));

#define LOG2E 1.44269504088896340736f

__device__ __forceinline__ void gload_lds16(const bf16* g, bf16* l) {
  __builtin_amdgcn_global_load_lds(
      (const __attribute__((address_space(1))) void*)g,
      (__attribute__((address_space(3))) void*)l, 16, 0, 0);
}

// ---------------- fp32 -> bf16 conversion (5 segments in one launch) -------
struct CvtArgs {
  const float* src[5];
  bf16* dst[5];
  int n[5];
};

__global__ __launch_bounds__(256) void cvt_multi(CvtArgs a) {
  const int seg = blockIdx.y;
  const float* __restrict__ s = a.src[seg];
  bf16* __restrict__ d = a.dst[seg];
  const int n = a.n[seg];
  int i = (blockIdx.x * 256 + threadIdx.x) * 4;
  const int stride = gridDim.x * 256 * 4;
  for (; i < n; i += stride) {
    float4 f = *reinterpret_cast<const float4*>(s + i);
    bf16x4 o = {(bf16)f.x, (bf16)f.y, (bf16)f.z, (bf16)f.w};
    *reinterpret_cast<bf16x4*>(d + i) = o;
  }
}

// ---------------- 128x128 bf16 GEMM, C = A * B^T + bias --------------------
struct GemmBatch {
  const bf16* Bw[3];
  const float* bias[3];
  void* C[3];
};

template <bool OUT_BF16>
__global__ __launch_bounds__(256, 2) void gemm128(const bf16* __restrict__ A,
                                                  GemmBatch gb, int M, int N,
                                                  int K) {
  const int tid = threadIdx.x;
  const int wid = tid >> 6;
  const int lane = tid & 63;
  const int l16 = lane & 15;
  const int hi = lane >> 4;
  const int m0 = blockIdx.x * 128;
  const int n0 = blockIdx.y * 128;
  const int z = blockIdx.z;
  const bf16* __restrict__ Bw = gb.Bw[z];
  const float* __restrict__ bias = gb.bias[z];

  __shared__ bf16 As[128 * 32];
  __shared__ bf16 Bs[128 * 32];

  f32x4 acc[4][4] = {};

  const int wm = (wid >> 1) * 64;
  const int wn = (wid & 1) * 64;

  for (int k0 = 0; k0 < K; k0 += 32) {
#pragma unroll
    for (int i = 0; i < 2; ++i) {
      const int chunk = wid + 4 * i;
      const int p = chunk * 1024 + lane * 16;
      const int row = p >> 6;
      const int cb = (p & 48) ^ ((row & 3) << 4);
      gload_lds16(A + (size_t)(m0 + row) * K + k0 + (cb >> 1), As + chunk * 512);
      gload_lds16(Bw + (size_t)(n0 + row) * K + k0 + (cb >> 1), Bs + chunk * 512);
    }
    __syncthreads();

    bf16x8 af[4], bfr[4];
#pragma unroll
    for (int m = 0; m < 4; ++m) {
      const int r = wm + m * 16 + l16;
      const int pb = r * 64 + ((hi * 16) ^ ((r & 3) << 4));
      af[m] = *reinterpret_cast<const bf16x8*>((const char*)As + pb);
    }
#pragma unroll
    for (int n = 0; n < 4; ++n) {
      const int r = wn + n * 16 + l16;
      const int pb = r * 64 + ((hi * 16) ^ ((r & 3) << 4));
      bfr[n] = *reinterpret_cast<const bf16x8*>((const char*)Bs + pb);
    }
#pragma unroll
    for (int m = 0; m < 4; ++m)
#pragma unroll
      for (int n = 0; n < 4; ++n)
        acc[m][n] =
            __builtin_amdgcn_mfma_f32_16x16x32_bf16(af[m], bfr[n], acc[m][n], 0, 0, 0);
    __syncthreads();
  }

  const int rbase = m0 + wm + hi * 4;
  const int cbase = n0 + wn + l16;
#pragma unroll
  for (int n = 0; n < 4; ++n) {
    const int col = cbase + n * 16;
    const float bv = bias[col];
#pragma unroll
    for (int m = 0; m < 4; ++m) {
#pragma unroll
      for (int j = 0; j < 4; ++j) {
        const int row = rbase + m * 16 + j;
        const float v = acc[m][n][j] + bv;
        if (OUT_BF16)
          ((bf16*)gb.C[z])[(size_t)row * N + col] = (bf16)v;
        else
          ((float*)gb.C[z])[(size_t)row * N + col] = v;
      }
    }
  }
}

// ---------------- causal flash attention, wave-split KV --------------------
// Block: one 32-row q-group, 4 waves. Wave w handles kv tiles {w, w+4, ...}.
// Swapped QK^T (S^T = K·Q^T via mfma(kf,qf)): lane owns q-col = lane&31.
// PV computes O^T = V^T·P via mfma(Vt-frag, P-frag): lane owns q again.
// No barriers in the main loop; one LDS combine at the end.
__global__ __launch_bounds__(256, 3) void attn_ws(const bf16* __restrict__ Q,
                                                  const bf16* __restrict__ K,
                                                  const bf16* __restrict__ V,
                                                  bf16* __restrict__ Y) {
  // XCD-contiguous remap + big-qg-first
  const int fid = blockIdx.x;                   // 0..2047
  const int lid = (fid & 7) * 256 + (fid >> 3); // XCD (fid&7) gets contiguous lid
  const int qg = 63 - (lid & 63);
  const int hb = lid >> 6;
  const int h = hb & 15;
  const int b = hb >> 4;

  const int tid = threadIdx.x;
  const int w = tid >> 6;
  const int lane = tid & 63;
  const int l31 = lane & 31;
  const int hi2 = lane >> 5;
  const size_t rb = (size_t)b * 2048;
  const int qbase = qg * 32;
  const int NT = qg + 1;  // kv tiles of 32
  const int hcol = h * 64;
  const float cl2 = 0.125f * LOG2E;

  // LDS: comb[4][32][66] f32 (33792 B) aliases the 4 per-wave Vt[64][40] bf16
  // (4*5120=20480 B). Time-separated by __syncthreads.
  __shared__ char smem[33792];
  __shared__ float mlS[4][2][32];
  bf16(*Vt)[40] = (bf16(*)[40])(smem + (size_t)w * 5120);
  float* combf = (float*)smem;

  // Q B-frags: lane: q=l31, d = kt*16 + hi2*8 + i
  bf16x8 qf[4];
  {
    const bf16* qp = Q + (rb + qbase + l31) * 1024 + hcol + hi2 * 8;
#pragma unroll
    for (int kt = 0; kt < 4; ++kt)
      qf[kt] = *reinterpret_cast<const bf16x8*>(qp + kt * 16);
  }

  f32x16 yac0 = {}, yac1 = {};  // O^T: lane q=l31, d=(r&3)+8*(r>>2)+4*hi2+32*da
  float m = -INFINITY, l = 0.f;

  const int kvg = lane & 7;   // staging: kv quad group
  const int dgr = lane >> 3;  // staging: d quad group (0..7)

  bf16x4 vr0[2][4], vr1[2][4];

  auto loadV = [&](bf16x4(&vr)[2][4], int t) {
    const bf16* vp = V + (rb + t * 32 + kvg * 4) * 1024 + hcol + dgr * 4;
#pragma unroll
    for (int r = 0; r < 2; ++r)
#pragma unroll
      for (int j = 0; j < 4; ++j)
        vr[r][j] = *reinterpret_cast<const bf16x4*>(vp + (size_t)j * 1024 + r * 32);
  };

  auto process = [&](bf16x4(&vr)[2][4], int t) {
    const int kvb = t * 32;
    // ---- transpose-write V^T into this wave's Vt ----
#pragma unroll
    for (int r = 0; r < 2; ++r)
#pragma unroll
      for (int kc = 0; kc < 4; ++kc) {
        bf16x4 wv = {vr[r][0][kc], vr[r][1][kc], vr[r][2][kc], vr[r][3][kc]};
        *reinterpret_cast<bf16x4*>(&Vt[r * 32 + dgr * 4 + kc][kvg * 4]) = wv;
      }
    // ---- K A-frags (direct global) + QK^T: sc = S^T[kv][q] ----
    const bf16* kp = K + (rb + kvb + l31) * 1024 + hcol + hi2 * 8;
    bf16x8 kf0 = *reinterpret_cast<const bf16x8*>(kp);
    bf16x8 kf1 = *reinterpret_cast<const bf16x8*>(kp + 16);
    bf16x8 kf2 = *reinterpret_cast<const bf16x8*>(kp + 32);
    bf16x8 kf3 = *reinterpret_cast<const bf16x8*>(kp + 48);
    f32x16 sc = {};
    sc = __builtin_amdgcn_mfma_f32_32x32x16_bf16(kf0, qf[0], sc, 0, 0, 0);
    sc = __builtin_amdgcn_mfma_f32_32x32x16_bf16(kf1, qf[1], sc, 0, 0, 0);
    sc = __builtin_amdgcn_mfma_f32_32x32x16_bf16(kf2, qf[2], sc, 0, 0, 0);
    sc = __builtin_amdgcn_mfma_f32_32x32x16_bf16(kf3, qf[3], sc, 0, 0, 0);

    // ---- causal mask (diagonal tile only; kvb == qbase there) ----
    if (t == qg) {
#pragma unroll
      for (int r = 0; r < 16; ++r) {
        const int kvl = (r & 3) + 8 * (r >> 2) + 4 * hi2;
        if (kvl > l31) sc[r] = -INFINITY;
      }
    }

    // ---- lane-local online softmax (lane owns q = l31; partner = lane^32) --
    float pm = sc[0];
#pragma unroll
    for (int r = 1; r < 16; ++r) pm = fmaxf(pm, sc[r]);
    pm = fmaxf(pm, __shfl_xor(pm, 32));

    if (!__all(pm <= m + 40.f)) {  // defer-max (T13): 40 raw = 7.2 exp2-units
      const float mn = fmaxf(m, pm);
      const float al = exp2f((m - mn) * cl2);
#pragma unroll
      for (int r = 0; r < 16; ++r) {
        yac0[r] *= al;
        yac1[r] *= al;
      }
      l *= al;
      m = mn;
    }
    float rs = 0.f;
    const float mc = m * cl2;
#pragma unroll
    for (int r = 0; r < 16; ++r) {
      const float p = exp2f(sc[r] * cl2 - mc);
      sc[r] = p;
      rs += p;
    }
    rs += __shfl_xor(rs, 32);
    l += rs;

    // ---- P -> bf16 frags in-register (pack + shfl_xor(32) + select) ----
    unsigned int pk[8];
#pragma unroll
    for (int i = 0; i < 8; ++i) {
      const unsigned short a = __builtin_bit_cast(unsigned short, (bf16)sc[2 * i]);
      const unsigned short c = __builtin_bit_cast(unsigned short, (bf16)sc[2 * i + 1]);
      pk[i] = (unsigned int)a | ((unsigned int)c << 16);
    }
    unsigned int s[8];
#pragma unroll
    for (int i = 0; i < 8; ++i) s[i] = (unsigned int)__shfl_xor((int)pk[i], 32);
    const u32x4 f0 = {hi2 ? s[2] : pk[0], hi2 ? s[3] : pk[1],
                      hi2 ? pk[2] : s[0], hi2 ? pk[3] : s[1]};
    const u32x4 f1 = {hi2 ? s[6] : pk[4], hi2 ? s[7] : pk[5],
                      hi2 ? pk[6] : s[4], hi2 ? pk[7] : s[5]};
    const bf16x8 pa0 = __builtin_bit_cast(bf16x8, f0);
    const bf16x8 pa1 = __builtin_bit_cast(bf16x8, f1);

    // ---- PV: O^T += V^T · P ----
    const bf16x8 va00 = *reinterpret_cast<const bf16x8*>(&Vt[l31][hi2 * 8]);
    const bf16x8 va10 = *reinterpret_cast<const bf16x8*>(&Vt[32 + l31][hi2 * 8]);
    yac0 = __builtin_amdgcn_mfma_f32_32x32x16_bf16(va00, pa0, yac0, 0, 0, 0);
    yac1 = __builtin_amdgcn_mfma_f32_32x32x16_bf16(va10, pa0, yac1, 0, 0, 0);
    const bf16x8 va01 = *reinterpret_cast<const bf16x8*>(&Vt[l31][16 + hi2 * 8]);
    const bf16x8 va11 = *reinterpret_cast<const bf16x8*>(&Vt[32 + l31][16 + hi2 * 8]);
    yac0 = __builtin_amdgcn_mfma_f32_32x32x16_bf16(va01, pa1, yac0, 0, 0, 0);
    yac1 = __builtin_amdgcn_mfma_f32_32x32x16_bf16(va11, pa1, yac1, 0, 0, 0);
  };

  // ---- main loop: 2-deep reg double-buffer for V (T14) ----
  int t = w;
  if (t < NT) {
    loadV(vr0, t);
    while (true) {
      int tn = t + 4;
      if (tn < NT) loadV(vr1, tn);
      process(vr0, t);
      t = tn;
      if (t >= NT) break;
      tn = t + 4;
      if (tn < NT) loadV(vr0, tn);
      process(vr1, t);
      t = tn;
      if (t >= NT) break;
    }
  }

  // ---- combine the 4 wave-partials ----
  __syncthreads();  // Vt dead; comb may now alias it
  if (lane < 32) {
    mlS[w][0][l31] = m;
    mlS[w][1][l31] = l;
  }
#pragma unroll
  for (int r = 0; r < 16; r += 2) {
    const int d0 = (r & 3) + 8 * (r >> 2) + 4 * hi2;
    float2 v2a;
    v2a.x = yac0[r];
    v2a.y = yac0[r + 1];
    *reinterpret_cast<float2*>(&combf[((size_t)w * 32 + l31) * 66 + d0]) = v2a;
    float2 v2b;
    v2b.x = yac1[r];
    v2b.y = yac1[r + 1];
    *reinterpret_cast<float2*>(&combf[((size_t)w * 32 + l31) * 66 + d0 + 32]) = v2b;
  }
  __syncthreads();

  const int tq = tid >> 3;
  const int dg = (tid & 7) * 8;
  float mw[4], lw[4];
#pragma unroll
  for (int ww = 0; ww < 4; ++ww) {
    mw[ww] = mlS[ww][0][tq];
    lw[ww] = mlS[ww][1][tq];
  }
  const float M = fmaxf(fmaxf(mw[0], mw[1]), fmaxf(mw[2], mw[3]));
  float Lsum = 0.f;
  float acc[8] = {};
#pragma unroll
  for (int ww = 0; ww < 4; ++ww) {
    const float wg = exp2f((mw[ww] - M) * cl2);
    Lsum += lw[ww] * wg;
#pragma unroll
    for (int j = 0; j < 8; ++j)
      acc[j] += wg * combf[((size_t)ww * 32 + tq) * 66 + dg + j];
  }
  const float inv = 1.f / Lsum;
  bf16x8 o;
#pragma unroll
  for (int j = 0; j < 8; ++j) o[j] = (bf16)(acc[j] * inv);
  *reinterpret_cast<bf16x8*>(Y + (rb + qbase + tq) * 1024 + hcol + dg) = o;
}

// ---------------- host launch ----------------------------------------------
extern "C" void kernel_launch(void* const* d_in, const int* in_sizes, int n_in,
                              void* d_out, int out_size, void* d_ws,
                              size_t ws_size, hipStream_t stream) {
  const float* x = (const float*)d_in[0];
  const float* Wq = (const float*)d_in[1];
  const float* bq = (const float*)d_in[2];
  const float* Wk = (const float*)d_in[3];
  const float* bk = (const float*)d_in[4];
  const float* Wv = (const float*)d_in[5];
  const float* bv = (const float*)d_in[6];
  const float* Wp = (const float*)d_in[7];
  const float* bp = (const float*)d_in[8];

  const int BS = 4096;
  const int Dm = 1024;

  char* ws = (char*)d_ws;
  bf16* xb = (bf16*)(ws);
  bf16* wqb = (bf16*)(ws + (size_t)(8 << 20));
  bf16* wkb = (bf16*)(ws + (size_t)(10 << 20));
  bf16* wvb = (bf16*)(ws + (size_t)(12 << 20));
  bf16* wpb = (bf16*)(ws + (size_t)(14 << 20));
  bf16* Qb = (bf16*)(ws + (size_t)(16 << 20));
  bf16* Kb = (bf16*)(ws + (size_t)(24 << 20));
  bf16* Vb = (bf16*)(ws + (size_t)(32 << 20));
  bf16* Yb = (bf16*)(ws + (size_t)(40 << 20));

  CvtArgs ca;
  ca.src[0] = x;  ca.dst[0] = xb;  ca.n[0] = BS * Dm;
  ca.src[1] = Wq; ca.dst[1] = wqb; ca.n[1] = Dm * Dm;
  ca.src[2] = Wk; ca.dst[2] = wkb; ca.n[2] = Dm * Dm;
  ca.src[3] = Wv; ca.dst[3] = wvb; ca.n[3] = Dm * Dm;
  ca.src[4] = Wp; ca.dst[4] = wpb; ca.n[4] = Dm * Dm;
  cvt_multi<<<dim3(1024, 5), 256, 0, stream>>>(ca);

  GemmBatch gq;
  gq.Bw[0] = wqb; gq.bias[0] = bq; gq.C[0] = Qb;
  gq.Bw[1] = wkb; gq.bias[1] = bk; gq.C[1] = Kb;
  gq.Bw[2] = wvb; gq.bias[2] = bv; gq.C[2] = Vb;
  gemm128<true><<<dim3(32, 8, 3), 256, 0, stream>>>(xb, gq, BS, Dm, Dm);

  attn_ws<<<dim3(2048), 256, 0, stream>>>(Qb, Kb, Vb, Yb);

  GemmBatch gp;
  gp.Bw[0] = wpb; gp.bias[0] = bp; gp.C[0] = d_out;
  gp.Bw[1] = wpb; gp.bias[1] = bp; gp.C[1] = d_out;
  gp.Bw[2] = wpb; gp.bias[2] = bp; gp.C[2] = d_out;
  gemm128<false><<<dim3(32, 8, 1), 256, 0, stream>>>(Yb, gp, BS, Dm, Dm);
}

// Round 6
// 162.960 us; speedup vs baseline: 1.4210x; 1.0720x over previous
//
#include <hip/hip_runtime.h>
#include <hip/hip_bf16.h>

typedef __bf16 bf16;
typedef bf16 bf16x4 __attribute__((ext_vector_type(4)));
typedef bf16 bf16x8 __attribute__((ext_vector_type(8)));
typedef float f32x4 __attribute__((ext_vector_type(4)));
typedef float f32x16 __attribute__((ext_vector_type(16)));
typedef unsigned int u32x4 __attribute__((ext_vector_type(4)));

#define LOG2E 1.44269504088896340736f

__device__ __forceinline__ void gload_lds16(const bf16* g, bf16* l) {
  __builtin_amdgcn_global_load_lds(
      (const __attribute__((address_space(1))) void*)g,
      (__attribute__((address_space(3))) void*)l, 16, 0, 0);
}

// raw v_exp_f32 (2^x): args here are always <= ~8, -inf ok (-> 0)
__device__ __forceinline__ float fexp2(float x) {
  float r;
  asm("v_exp_f32 %0, %1" : "=v"(r) : "v"(x));
  return r;
}

// ---------------- fp32 -> bf16 conversion (5 segments in one launch) -------
struct CvtArgs {
  const float* src[5];
  bf16* dst[5];
  int n[5];
};

__global__ __launch_bounds__(256) void cvt_multi(CvtArgs a) {
  const int seg = blockIdx.y;
  const float* __restrict__ s = a.src[seg];
  bf16* __restrict__ d = a.dst[seg];
  const int n = a.n[seg];
  int i = (blockIdx.x * 256 + threadIdx.x) * 4;
  const int stride = gridDim.x * 256 * 4;
  for (; i < n; i += stride) {
    float4 f = *reinterpret_cast<const float4*>(s + i);
    bf16x4 o = {(bf16)f.x, (bf16)f.y, (bf16)f.z, (bf16)f.w};
    *reinterpret_cast<bf16x4*>(d + i) = o;
  }
}

// ---------------- 128x128 bf16 GEMM, C = A * B^T + bias --------------------
struct GemmBatch {
  const bf16* Bw[3];
  const float* bias[3];
  void* C[3];
};

template <bool OUT_BF16>
__global__ __launch_bounds__(256, 2) void gemm128(const bf16* __restrict__ A,
                                                  GemmBatch gb, int M, int N,
                                                  int K) {
  const int tid = threadIdx.x;
  const int wid = tid >> 6;
  const int lane = tid & 63;
  const int l16 = lane & 15;
  const int hi = lane >> 4;
  const int m0 = blockIdx.x * 128;
  const int n0 = blockIdx.y * 128;
  const int z = blockIdx.z;
  const bf16* __restrict__ Bw = gb.Bw[z];
  const float* __restrict__ bias = gb.bias[z];

  __shared__ bf16 As[128 * 32];
  __shared__ bf16 Bs[128 * 32];

  f32x4 acc[4][4] = {};

  const int wm = (wid >> 1) * 64;
  const int wn = (wid & 1) * 64;

  for (int k0 = 0; k0 < K; k0 += 32) {
#pragma unroll
    for (int i = 0; i < 2; ++i) {
      const int chunk = wid + 4 * i;
      const int p = chunk * 1024 + lane * 16;
      const int row = p >> 6;
      const int cb = (p & 48) ^ ((row & 3) << 4);
      gload_lds16(A + (size_t)(m0 + row) * K + k0 + (cb >> 1), As + chunk * 512);
      gload_lds16(Bw + (size_t)(n0 + row) * K + k0 + (cb >> 1), Bs + chunk * 512);
    }
    __syncthreads();

    bf16x8 af[4], bfr[4];
#pragma unroll
    for (int m = 0; m < 4; ++m) {
      const int r = wm + m * 16 + l16;
      const int pb = r * 64 + ((hi * 16) ^ ((r & 3) << 4));
      af[m] = *reinterpret_cast<const bf16x8*>((const char*)As + pb);
    }
#pragma unroll
    for (int n = 0; n < 4; ++n) {
      const int r = wn + n * 16 + l16;
      const int pb = r * 64 + ((hi * 16) ^ ((r & 3) << 4));
      bfr[n] = *reinterpret_cast<const bf16x8*>((const char*)Bs + pb);
    }
#pragma unroll
    for (int m = 0; m < 4; ++m)
#pragma unroll
      for (int n = 0; n < 4; ++n)
        acc[m][n] =
            __builtin_amdgcn_mfma_f32_16x16x32_bf16(af[m], bfr[n], acc[m][n], 0, 0, 0);
    __syncthreads();
  }

  const int rbase = m0 + wm + hi * 4;
  const int cbase = n0 + wn + l16;
#pragma unroll
  for (int n = 0; n < 4; ++n) {
    const int col = cbase + n * 16;
    const float bv = bias[col];
#pragma unroll
    for (int m = 0; m < 4; ++m) {
#pragma unroll
      for (int j = 0; j < 4; ++j) {
        const int row = rbase + m * 16 + j;
        const float v = acc[m][n][j] + bv;
        if (OUT_BF16)
          ((bf16*)gb.C[z])[(size_t)row * N + col] = (bf16)v;
        else
          ((float*)gb.C[z])[(size_t)row * N + col] = v;
      }
    }
  }
}

// ---------------- causal flash attention, wave-split KV, paired q-groups ---
// 1024 blocks; block p handles (b,h)=p&31 for q-groups 63-(p>>5) then (p>>5):
// uniform 65 KV-tiles per block. Within a pass, wave w takes kv tiles
// {w, w+4, ...}; K and V both 2-deep register-prefetched; no main-loop
// barriers; LDS combine per pass.
__global__ __launch_bounds__(256, 3) void attn_ws(const bf16* __restrict__ Q,
                                                  const bf16* __restrict__ K,
                                                  const bf16* __restrict__ V,
                                                  bf16* __restrict__ Y) {
  const int p = blockIdx.x;    // 0..1023
  const int bh = p & 31;       // XCD gets fixed {bh mod 8} streams
  const int j = p >> 5;        // 0..31
  const int h = bh & 15;
  const int b = bh >> 4;

  const int tid = threadIdx.x;
  const int w = tid >> 6;
  const int lane = tid & 63;
  const int l31 = lane & 31;
  const int hi2 = lane >> 5;
  const size_t rb = (size_t)b * 2048;
  const int hcol = h * 64;
  const float cl2 = 0.125f * LOG2E;

  // comb[4][32][66] f32 (33792 B) aliases 4 per-wave Vt[64][40] bf16 (20480 B)
  __shared__ char smem[33792];
  __shared__ float mlS[4][2][32];
  bf16(*Vt)[40] = (bf16(*)[40])(smem + (size_t)w * 5120);
  float* combf = (float*)smem;

  const int kvg = lane & 7;   // staging: kv quad group
  const int dgr = lane >> 3;  // staging: d quad group (0..7)

  bf16x4 vr0[2][4], vr1[2][4];
  bf16x8 kr0[4], kr1[4];

  auto loadV = [&](bf16x4(&vr)[2][4], int t) {
    const bf16* vp = V + (rb + t * 32 + kvg * 4) * 1024 + hcol + dgr * 4;
#pragma unroll
    for (int r = 0; r < 2; ++r)
#pragma unroll
      for (int jj = 0; jj < 4; ++jj)
        vr[r][jj] = *reinterpret_cast<const bf16x4*>(vp + (size_t)jj * 1024 + r * 32);
  };
  auto loadK = [&](bf16x8(&kr)[4], int t) {
    const bf16* kp = K + (rb + t * 32 + l31) * 1024 + hcol + hi2 * 8;
    kr[0] = *reinterpret_cast<const bf16x8*>(kp);
    kr[1] = *reinterpret_cast<const bf16x8*>(kp + 16);
    kr[2] = *reinterpret_cast<const bf16x8*>(kp + 32);
    kr[3] = *reinterpret_cast<const bf16x8*>(kp + 48);
  };

  auto run = [&](int qg) {
    const int qbase = qg * 32;
    const int NT = qg + 1;

    // Q B-frags: lane: q=l31, d = kt*16 + hi2*8 + i
    bf16x8 qf[4];
    {
      const bf16* qp = Q + (rb + qbase + l31) * 1024 + hcol + hi2 * 8;
#pragma unroll
      for (int kt = 0; kt < 4; ++kt)
        qf[kt] = *reinterpret_cast<const bf16x8*>(qp + kt * 16);
    }

    f32x16 yac0 = {}, yac1 = {};  // O^T: q=l31, d=(r&3)+8*(r>>2)+4*hi2+32*da
    float m = -INFINITY, l = 0.f;

    auto process = [&](bf16x4(&vr)[2][4], bf16x8(&kr)[4], int t) {
      // ---- transpose-write V^T into this wave's Vt ----
#pragma unroll
      for (int r = 0; r < 2; ++r)
#pragma unroll
        for (int kc = 0; kc < 4; ++kc) {
          bf16x4 wv = {vr[r][0][kc], vr[r][1][kc], vr[r][2][kc], vr[r][3][kc]};
          *reinterpret_cast<bf16x4*>(&Vt[r * 32 + dgr * 4 + kc][kvg * 4]) = wv;
        }
      // ---- QK^T: sc = S^T[kv][q] ----
      f32x16 sc = {};
      sc = __builtin_amdgcn_mfma_f32_32x32x16_bf16(kr[0], qf[0], sc, 0, 0, 0);
      sc = __builtin_amdgcn_mfma_f32_32x32x16_bf16(kr[1], qf[1], sc, 0, 0, 0);
      sc = __builtin_amdgcn_mfma_f32_32x32x16_bf16(kr[2], qf[2], sc, 0, 0, 0);
      sc = __builtin_amdgcn_mfma_f32_32x32x16_bf16(kr[3], qf[3], sc, 0, 0, 0);

      // ---- causal mask (diagonal tile only) ----
      if (t == qg) {
#pragma unroll
        for (int r = 0; r < 16; ++r) {
          const int kvl = (r & 3) + 8 * (r >> 2) + 4 * hi2;
          if (kvl > l31) sc[r] = -INFINITY;
        }
      }

      // ---- lane-local online softmax (lane owns q=l31; partner lane^32) ----
      float red[8];
#pragma unroll
      for (int i = 0; i < 8; ++i) red[i] = fmaxf(sc[i], sc[i + 8]);
#pragma unroll
      for (int i = 0; i < 4; ++i) red[i] = fmaxf(red[i], red[i + 4]);
      float pm = fmaxf(fmaxf(red[0], red[1]), fmaxf(red[2], red[3]));
      pm = fmaxf(pm, __shfl_xor(pm, 32));

      if (!__all(pm <= m + 40.f)) {  // defer-max (T13)
        const float mn = fmaxf(m, pm);
        const float al = fexp2((m - mn) * cl2);
#pragma unroll
        for (int r = 0; r < 16; ++r) {
          yac0[r] *= al;
          yac1[r] *= al;
        }
        l *= al;
        m = mn;
      }
      float ps[16];
      const float mc = m * cl2;
#pragma unroll
      for (int r = 0; r < 16; ++r) ps[r] = fexp2(sc[r] * cl2 - mc);
      float sum8[8];
#pragma unroll
      for (int i = 0; i < 8; ++i) sum8[i] = ps[i] + ps[i + 8];
#pragma unroll
      for (int i = 0; i < 4; ++i) sum8[i] += sum8[i + 4];
      float rs = (sum8[0] + sum8[1]) + (sum8[2] + sum8[3]);
      rs += __shfl_xor(rs, 32);
      l += rs;

      // ---- P -> bf16 frags in-register (pack + shfl_xor(32) + select) ----
      unsigned int pk[8];
#pragma unroll
      for (int i = 0; i < 8; ++i) {
        const unsigned short a = __builtin_bit_cast(unsigned short, (bf16)ps[2 * i]);
        const unsigned short c = __builtin_bit_cast(unsigned short, (bf16)ps[2 * i + 1]);
        pk[i] = (unsigned int)a | ((unsigned int)c << 16);
      }
      unsigned int s[8];
#pragma unroll
      for (int i = 0; i < 8; ++i) s[i] = (unsigned int)__shfl_xor((int)pk[i], 32);
      const u32x4 f0 = {hi2 ? s[2] : pk[0], hi2 ? s[3] : pk[1],
                        hi2 ? pk[2] : s[0], hi2 ? pk[3] : s[1]};
      const u32x4 f1 = {hi2 ? s[6] : pk[4], hi2 ? s[7] : pk[5],
                        hi2 ? pk[6] : s[4], hi2 ? pk[7] : s[5]};
      const bf16x8 pa0 = __builtin_bit_cast(bf16x8, f0);
      const bf16x8 pa1 = __builtin_bit_cast(bf16x8, f1);

      // ---- PV: O^T += V^T · P ----
      const bf16x8 va00 = *reinterpret_cast<const bf16x8*>(&Vt[l31][hi2 * 8]);
      const bf16x8 va10 = *reinterpret_cast<const bf16x8*>(&Vt[32 + l31][hi2 * 8]);
      yac0 = __builtin_amdgcn_mfma_f32_32x32x16_bf16(va00, pa0, yac0, 0, 0, 0);
      yac1 = __builtin_amdgcn_mfma_f32_32x32x16_bf16(va10, pa0, yac1, 0, 0, 0);
      const bf16x8 va01 = *reinterpret_cast<const bf16x8*>(&Vt[l31][16 + hi2 * 8]);
      const bf16x8 va11 = *reinterpret_cast<const bf16x8*>(&Vt[32 + l31][16 + hi2 * 8]);
      yac0 = __builtin_amdgcn_mfma_f32_32x32x16_bf16(va01, pa1, yac0, 0, 0, 0);
      yac1 = __builtin_amdgcn_mfma_f32_32x32x16_bf16(va11, pa1, yac1, 0, 0, 0);
    };

    // ---- main loop: 2-deep reg double-buffer for K and V ----
    int t = w;
    if (t < NT) {
      loadV(vr0, t);
      loadK(kr0, t);
      while (true) {
        int tn = t + 4;
        if (tn < NT) {
          loadV(vr1, tn);
          loadK(kr1, tn);
        }
        process(vr0, kr0, t);
        t = tn;
        if (t >= NT) break;
        tn = t + 4;
        if (tn < NT) {
          loadV(vr0, tn);
          loadK(kr0, tn);
        }
        process(vr1, kr1, t);
        t = tn;
        if (t >= NT) break;
      }
    }

    // ---- combine the 4 wave-partials ----
    __syncthreads();  // Vt dead; comb may now alias it
    if (lane < 32) {
      mlS[w][0][l31] = m;
      mlS[w][1][l31] = l;
    }
#pragma unroll
    for (int r = 0; r < 16; r += 2) {
      const int d0 = (r & 3) + 8 * (r >> 2) + 4 * hi2;
      float2 v2a;
      v2a.x = yac0[r];
      v2a.y = yac0[r + 1];
      *reinterpret_cast<float2*>(&combf[((size_t)w * 32 + l31) * 66 + d0]) = v2a;
      float2 v2b;
      v2b.x = yac1[r];
      v2b.y = yac1[r + 1];
      *reinterpret_cast<float2*>(&combf[((size_t)w * 32 + l31) * 66 + d0 + 32]) = v2b;
    }
    __syncthreads();

    const int tq = tid >> 3;
    const int dg = (tid & 7) * 8;
    float mw[4], lw[4];
#pragma unroll
    for (int ww = 0; ww < 4; ++ww) {
      mw[ww] = mlS[ww][0][tq];
      lw[ww] = mlS[ww][1][tq];
    }
    const float M = fmaxf(fmaxf(mw[0], mw[1]), fmaxf(mw[2], mw[3]));
    float Lsum = 0.f;
    float acc[8] = {};
#pragma unroll
    for (int ww = 0; ww < 4; ++ww) {
      const float wg = fexp2((mw[ww] - M) * cl2);
      Lsum += lw[ww] * wg;
#pragma unroll
      for (int jj = 0; jj < 8; ++jj)
        acc[jj] += wg * combf[((size_t)ww * 32 + tq) * 66 + dg + jj];
    }
    const float inv = 1.f / Lsum;
    bf16x8 o;
#pragma unroll
    for (int jj = 0; jj < 8; ++jj) o[jj] = (bf16)(acc[jj] * inv);
    *reinterpret_cast<bf16x8*>(Y + (rb + qbase + tq) * 1024 + hcol + dg) = o;
    __syncthreads();  // comb reads done before next pass rewrites Vt
  };

  run(63 - j);
  run(j);
}

// ---------------- host launch ----------------------------------------------
extern "C" void kernel_launch(void* const* d_in, const int* in_sizes, int n_in,
                              void* d_out, int out_size, void* d_ws,
                              size_t ws_size, hipStream_t stream) {
  const float* x = (const float*)d_in[0];
  const float* Wq = (const float*)d_in[1];
  const float* bq = (const float*)d_in[2];
  const float* Wk = (const float*)d_in[3];
  const float* bk = (const float*)d_in[4];
  const float* Wv = (const float*)d_in[5];
  const float* bv = (const float*)d_in[6];
  const float* Wp = (const float*)d_in[7];
  const float* bp = (const float*)d_in[8];

  const int BS = 4096;
  const int Dm = 1024;

  char* ws = (char*)d_ws;
  bf16* xb = (bf16*)(ws);
  bf16* wqb = (bf16*)(ws + (size_t)(8 << 20));
  bf16* wkb = (bf16*)(ws + (size_t)(10 << 20));
  bf16* wvb = (bf16*)(ws + (size_t)(12 << 20));
  bf16* wpb = (bf16*)(ws + (size_t)(14 << 20));
  bf16* Qb = (bf16*)(ws + (size_t)(16 << 20));
  bf16* Kb = (bf16*)(ws + (size_t)(24 << 20));
  bf16* Vb = (bf16*)(ws + (size_t)(32 << 20));
  bf16* Yb = (bf16*)(ws + (size_t)(40 << 20));

  CvtArgs ca;
  ca.src[0] = x;  ca.dst[0] = xb;  ca.n[0] = BS * Dm;
  ca.src[1] = Wq; ca.dst[1] = wqb; ca.n[1] = Dm * Dm;
  ca.src[2] = Wk; ca.dst[2] = wkb; ca.n[2] = Dm * Dm;
  ca.src[3] = Wv; ca.dst[3] = wvb; ca.n[3] = Dm * Dm;
  ca.src[4] = Wp; ca.dst[4] = wpb; ca.n[4] = Dm * Dm;
  cvt_multi<<<dim3(1024, 5), 256, 0, stream>>>(ca);

  GemmBatch gq;
  gq.Bw[0] = wqb; gq.bias[0] = bq; gq.C[0] = Qb;
  gq.Bw[1] = wkb; gq.bias[1] = bk; gq.C[1] = Kb;
  gq.Bw[2] = wvb; gq.bias[2] = bv; gq.C[2] = Vb;
  gemm128<true><<<dim3(32, 8, 3), 256, 0, stream>>>(xb, gq, BS, Dm, Dm);

  attn_ws<<<dim3(1024), 256, 0, stream>>>(Qb, Kb, Vb, Yb);

  GemmBatch gp;
  gp.Bw[0] = wpb; gp.bias[0] = bp; gp.C[0] = d_out;
  gp.Bw[1] = wpb; gp.bias[1] = bp; gp.C[1] = d_out;
  gp.Bw[2] = wpb; gp.bias[2] = bp; gp.C[2] = d_out;
  gemm128<false><<<dim3(32, 8, 1), 256, 0, stream>>>(Yb, gp, BS, Dm, Dm);
}